// Round 5
// baseline (391.837 us; speedup 1.0000x reference)
//
#include <hip/hip_runtime.h>
#include <hip/hip_cooperative_groups.h>

namespace cg = cooperative_groups;

#define BD 8192
#define DD 512
#define PLANE (BD * DD)          // 4194304 elems per bf16 plane
#define NPLANES 5                // 0:A1 1:A2 2:A3 3:x 4:x^2
#define KSPLIT 32
#define NELEM (DD * DD)          // 262144

typedef __attribute__((ext_vector_type(4))) float f32x4;
typedef __attribute__((ext_vector_type(8))) short short8;

__device__ __forceinline__ float polyev2(float c0, float c1, float c2, float w, float w2) {
    return c0 + c1 * w + c2 * w2;
}

// float -> bf16 bits, round-to-nearest-even
__device__ __forceinline__ unsigned short f2b(float v) {
    unsigned u = __builtin_bit_cast(unsigned, v);
    u += 0x7FFFu + ((u >> 16) & 1u);
    return (unsigned short)(u >> 16);
}

__device__ __forceinline__ void gload_lds16(const unsigned short* g, unsigned short* l) {
    __builtin_amdgcn_global_load_lds((__attribute__((address_space(1))) const void*)g,
                                     (__attribute__((address_space(3))) void*)l, 16, 0, 0);
}

// ===========================================================================
// Plane layout (bf16): elem addr = p*PLANE + (bt*512 + C)*64 + ((k>>3)^(C&7))*8 + (k&7)
//   bt = K-tile of 64 rows, C = column, k = row%64. XOR slot swizzle makes the
//   gemm ds_read_b128 column-slice reads bank-conflict-free; global image IS the
//   LDS image so gload_lds stages linearly (both-sides-or-neither, rule #21).
// ===========================================================================

// One 64-row x 64-col prep unit (verified R4 math). Uses 40960 B of L.
__device__ __forceinline__ void prep_unit(
    const float* __restrict__ x, const float* __restrict__ s,
    const float* __restrict__ y, const float* __restrict__ pw,
    unsigned short* __restrict__ pl, float* __restrict__ csp,
    const int colq, const int bt, char* L)
{
    const int t      = threadIdx.x;
    const int colL4  = (t & 15) * 4;
    const int rg     = t >> 4;
    const int kl     = rg * 4;
    const int c0     = colq * 64;
    const int r0     = bt * 64;

    const float p23 = pw[23], p24 = pw[24], p25 = pw[25], p26 = pw[26], p27 = pw[27];
    const float p28 = pw[28], p29 = pw[29], p32 = pw[32], p33 = pw[33];

    float sm[12][4];
#pragma unroll
    for (int v = 0; v < 12; ++v)
#pragma unroll
        for (int cc = 0; cc < 4; ++cc) sm[v][cc] = 0.f;

    unsigned pk[NPLANES][4][2];

#pragma unroll
    for (int j = 0; j < 4; ++j) {
        const int row = r0 + kl + j;
        const float4 xv = *(const float4*)&x[(size_t)row * DD + c0 + colL4];
        const float4 sv = *(const float4*)&s[(size_t)row * DD + c0 + colL4];
        const float4 yv = *(const float4*)&y[(size_t)row * DD + c0 + colL4];
        const float xa[4] = {xv.x, xv.y, xv.z, xv.w};
        const float sa[4] = {sv.x, sv.y, sv.z, sv.w};
        const float ya[4] = {yv.x, yv.y, yv.z, yv.w};
#pragma unroll
        for (int cc = 0; cc < 4; ++cc) {
            const float X = xa[cc], S = sa[cc], Y = ya[cc];
            const float X2 = X * X, S2 = S * S, Y2 = Y * Y, SY = S * Y;
            sm[0][cc] += X;  sm[1][cc] += X2;      sm[2][cc] += X2 * X;
            sm[3][cc] += S;  sm[4][cc] += S2;      sm[5][cc] += S2 * S;
            sm[6][cc] += Y;  sm[7][cc] += Y2;      sm[8][cc] += Y2 * Y;
            sm[9][cc] += SY; sm[10][cc] += S2 * Y; sm[11][cc] += S * Y2;
            unsigned short tv[NPLANES];
            tv[0] = f2b(p26 * S + p23 * Y + p29 * S2 + p25 * Y2 + p28 * SY);
            tv[1] = f2b(p33 * S + p32 * Y);
            tv[2] = f2b(p27 * S + p24 * Y);
            tv[3] = f2b(X);
            tv[4] = f2b(X2);
            if ((j & 1) == 0) {
#pragma unroll
                for (int p = 0; p < NPLANES; ++p) pk[p][cc][j >> 1] = (unsigned)tv[p];
            } else {
#pragma unroll
                for (int p = 0; p < NPLANES; ++p) pk[p][cc][j >> 1] |= (unsigned)tv[p] << 16;
            }
        }
    }

    __syncthreads();   // protect any previous LDS readers (re-used buffer)

#pragma unroll
    for (int p = 0; p < NPLANES; ++p) {
#pragma unroll
        for (int cc = 0; cc < 4; ++cc) {
            const int colL = colL4 + cc;
            const int addr = p * 8192 + colL * 128 + (((kl >> 3) ^ (colL & 7)) << 4) + ((kl & 4) << 1);
            uint2 u; u.x = pk[p][cc][0]; u.y = pk[p][cc][1];
            *(uint2*)&L[addr] = u;
        }
    }
    __syncthreads();

    // contiguous LDS -> global copy: 10 x 16B per thread
    {
        char* gbase = (char*)pl;
        const size_t blockByte = ((size_t)bt * DD + c0) * 128;
#pragma unroll
        for (int u = 0; u < 10; ++u) {
            const int byteoff = u * 4096 + t * 16;
            const int p = byteoff >> 13;
            const int within = byteoff & 8191;
            *(uint4*)(gbase + ((size_t)p * PLANE) * 2 + blockByte + within) =
                *(const uint4*)&L[byteoff];
        }
    }
    __syncthreads();

    // column sums: in-wave (^16,^32) then cross-wave via LDS
#pragma unroll
    for (int v = 0; v < 12; ++v)
#pragma unroll
        for (int cc = 0; cc < 4; ++cc) {
            sm[v][cc] += __shfl_xor(sm[v][cc], 16, 64);
            sm[v][cc] += __shfl_xor(sm[v][cc], 32, 64);
        }
    float* R = (float*)L;
    const int wv = t >> 6, ln = t & 63;
    if (ln < 16) {
#pragma unroll
        for (int v = 0; v < 12; ++v)
#pragma unroll
            for (int cc = 0; cc < 4; ++cc)
                R[(wv * 16 + ln) * 48 + v * 4 + cc] = sm[v][cc];
    }
    __syncthreads();
    if (t < 16) {
        const int blk = bt * 8 + colq;
#pragma unroll
        for (int v = 0; v < 12; ++v)
#pragma unroll
            for (int cc = 0; cc < 4; ++cc) {
                float a = R[(0 * 16 + t) * 48 + v * 4 + cc]
                        + R[(1 * 16 + t) * 48 + v * 4 + cc]
                        + R[(2 * 16 + t) * 48 + v * 4 + cc]
                        + R[(3 * 16 + t) * 48 + v * 4 + cc];
                csp[((size_t)blk * 12 + v) * 64 + t * 4 + cc] = a;
            }
    }
}

// --------------------------- fused 2-acc GEMM body -------------------------
__device__ __forceinline__ void do_tile(
    const unsigned short* __restrict__ A, const unsigned short* __restrict__ B,
    int wo, int wi, int l15, int g4, f32x4 (&acc)[4][4])
{
#pragma unroll
    for (int ss = 0; ss < 2; ++ss) {
        short8 af[4], bf[4];
#pragma unroll
        for (int m = 0; m < 4; ++m) {
            const int r = wo + m * 16 + l15;
            af[m] = *(const short8*)((const char*)A + (r << 7) + ((((ss << 2) + g4) ^ (r & 7)) << 4));
        }
#pragma unroll
        for (int n = 0; n < 4; ++n) {
            const int r = wi + n * 16 + l15;
            bf[n] = *(const short8*)((const char*)B + (r << 7) + ((((ss << 2) + g4) ^ (r & 7)) << 4));
        }
#pragma unroll
        for (int m = 0; m < 4; ++m)
#pragma unroll
            for (int n = 0; n < 4; ++n)
                acc[m][n] = __builtin_amdgcn_mfma_f32_16x16x32_bf16(af[m], bf[n], acc[m][n], 0, 0, 0);
    }
}

// bid in [0,512): ks = (bid&7) + 8*(bid>>7), tile = (bid>>3)&15. ldsp = 4*8192 shorts.
__device__ __forceinline__ void gemm_body(
    const unsigned short* __restrict__ pl, const float* __restrict__ w,
    float* __restrict__ part, const int bid, unsigned short* ldsp)
{
    const int t    = threadIdx.x;
    const int lane = t & 63;
    const int wid  = t >> 6;
    const int ks   = (bid & 7) + ((bid >> 7) << 3);
    const int tile = (bid >> 3) & 15;
    const int tileI = tile & 3;
    const int tileO = tile >> 2;
    const int wo = (wid >> 1) * 64, wi = (wid & 1) * 64;
    const int l15 = lane & 15, g4 = lane >> 4;

    const unsigned short* Am = pl + (size_t)(ks < 16 ? 0 : 1) * PLANE;
    const unsigned short* Bm = pl + (size_t)(ks < 16 ? 3 : 4) * PLANE;
    const unsigned short* Aw = pl + (size_t)2 * PLANE;
    const unsigned short* Bx = pl + (size_t)3 * PLANE;
    const int btm0 = (ks & 15) * 8;
    const int btw0 = ks * 4;

    f32x4 accM[4][4], accW[4][4];
#pragma unroll
    for (int m = 0; m < 4; ++m)
#pragma unroll
        for (int n = 0; n < 4; ++n) { accM[m][n] = (f32x4)0.f; accW[m][n] = (f32x4)0.f; }

    auto Abase = [&](int j) -> const unsigned short* {
        return (j < 8) ? Am + ((size_t)(btm0 + j) * DD + tileO * 128) * 64
                       : Aw + ((size_t)(btw0 + j - 8) * DD + tileO * 128) * 64;
    };
    auto Bbase = [&](int j) -> const unsigned short* {
        return (j < 8) ? Bm + ((size_t)(btm0 + j) * DD + tileI * 128) * 64
                       : Bx + ((size_t)(btw0 + j - 8) * DD + tileI * 128) * 64;
    };
    auto stage = [&](const unsigned short* Ag, const unsigned short* Bg, int buf) {
        unsigned short* La = ldsp + (buf * 2 + 0) * 8192;
        unsigned short* Lb = ldsp + (buf * 2 + 1) * 8192;
#pragma unroll
        for (int c = 0; c < 4; ++c) {
            gload_lds16(Ag + c * 2048 + t * 8, La + c * 2048 + wid * 512);
            gload_lds16(Bg + c * 2048 + t * 8, Lb + c * 2048 + wid * 512);
        }
    };

    stage(Abase(0), Bbase(0), 0);
    __syncthreads();
#pragma unroll 1
    for (int j = 0; j < 8; ++j) {
        const int cur = j & 1;
        stage(Abase(j + 1), Bbase(j + 1), cur ^ 1);
        do_tile(ldsp + (cur * 2 + 0) * 8192, ldsp + (cur * 2 + 1) * 8192, wo, wi, l15, g4, accM);
        __syncthreads();
    }
#pragma unroll 1
    for (int j = 8; j < 12; ++j) {
        const int cur = j & 1;
        if (j < 11) stage(Abase(j + 1), Bbase(j + 1), cur ^ 1);
        do_tile(ldsp + (cur * 2 + 0) * 8192, ldsp + (cur * 2 + 1) * 8192, wo, wi, l15, g4, accW);
        __syncthreads();
    }

    float* pout = part + (size_t)ks * NELEM;
#pragma unroll
    for (int m = 0; m < 4; ++m) {
        const int o = tileO * 128 + wo + m * 16 + g4 * 4;
#pragma unroll
        for (int n = 0; n < 4; ++n) {
            const int i = tileI * 128 + wi + n * 16 + l15;
#pragma unroll
            for (int r = 0; r < 4; ++r) {
                const float wv = w[(size_t)(o + r) * DD + i];
                pout[(size_t)(o + r) * DD + i] = accM[m][n][r] + wv * accW[m][n][r];
            }
        }
    }
}

// ------------------------- epilogue element bodies -------------------------
__device__ __forceinline__ void rank1_store(
    const int idx, const float* __restrict__ part, const float* __restrict__ w,
    const float* __restrict__ pw, const float* __restrict__ cs, float* __restrict__ out)
{
    const int o = idx >> 9;
    const int i = idx & 511;
    float g = 0.f;
#pragma unroll
    for (int ks = 0; ks < KSPLIT; ++ks) g += part[(size_t)ks * NELEM + idx];
    const float wv = w[idx];
    const float w2 = wv * wv, w3 = w2 * wv;
    float acc = (float)BD * (pw[0] + pw[1] * wv + pw[2] * w2 + pw[3] * w3);
    acc += cs[0 * DD + i] * polyev2(pw[20], pw[21], pw[22], wv, w2);
    acc += cs[1 * DD + i] * (pw[30] + pw[31] * wv);
    acc += cs[2 * DD + i] * pw[34];
    acc += cs[6 * DD + o]  * polyev2(pw[4],  pw[5],  pw[6],  wv, w2);
    acc += cs[7 * DD + o]  * (pw[7] + pw[8] * wv);
    acc += cs[8 * DD + o]  * pw[9];
    acc += cs[3 * DD + o]  * polyev2(pw[10], pw[11], pw[12], wv, w2);
    acc += cs[9 * DD + o]  * (pw[13] + pw[14] * wv);
    acc += cs[11 * DD + o] * pw[15];
    acc += cs[4 * DD + o]  * (pw[16] + pw[17] * wv);
    acc += cs[10 * DD + o] * pw[18];
    acc += cs[5 * DD + o]  * pw[19];
    out[idx] = (1.0f / (float)BD) * (g + acc);
}

__device__ __forceinline__ void deltab_store(
    const int o, const float* __restrict__ bvec, const float* __restrict__ pb,
    const float* __restrict__ cs, float* __restrict__ out)
{
    const float bv = bvec[o];
    const float b2 = bv * bv, b3 = b2 * bv;
    const float invB = 1.0f / (float)BD;
    float acc = (float)BD * (pb[0] + pb[1] * bv + pb[2] * b2 + pb[3] * b3);
    acc += cs[6 * DD + o] * (pb[4] + pb[5] * bv + pb[6] * b2);
    acc += cs[7 * DD + o] * (pb[7] + pb[8] * bv);
    acc += cs[8 * DD + o] * pb[9];
    out[DD * DD + o] = invB * acc;
}

// ===========================================================================
// Cooperative single-launch kernel: prep -> sync -> cs+gemm -> sync -> epilogue
// ===========================================================================
__global__ __launch_bounds__(256, 2) void fused_all(
    const float* __restrict__ x, const float* __restrict__ s,
    const float* __restrict__ y, const float* __restrict__ w,
    const float* __restrict__ bvec, const float* __restrict__ pw,
    const float* __restrict__ pb,
    unsigned short* __restrict__ pl, float* __restrict__ part,
    float* __restrict__ csp, float* __restrict__ cs, float* __restrict__ out)
{
    __shared__ __align__(16) char L[65536];
    const int bid = blockIdx.x;
    const int t   = threadIdx.x;
    cg::grid_group grid = cg::this_grid();

    // Phase A: two 64x64 prep units per block (1024 units total)
    prep_unit(x, s, y, pw, pl, csp, (2 * bid) & 7,     (2 * bid) >> 3,     L);
    prep_unit(x, s, y, pw, pl, csp, (2 * bid + 1) & 7, (2 * bid + 1) >> 3, L);

    __threadfence();
    grid.sync();

    // Phase B1: this block's 12 column-sum entries (6144 total = 512*12)
    {
        float* red = (float*)L;
        if (t < 192) {
            const int e = t >> 4, j = t & 15;
            const int u = bid * 12 + e;
            const int v = u >> 9, c = u & 511;
            const int cq = c >> 6, cl = c & 63;
            float p = 0.f;
#pragma unroll
            for (int k = 0; k < 8; ++k) {
                const int bt = j * 8 + k;
                p += csp[((size_t)(bt * 8 + cq) * 12 + v) * 64 + cl];
            }
            red[e * 16 + j] = p;
        }
        __syncthreads();
        if (t < 12) {
            float a = 0.f;
#pragma unroll
            for (int j2 = 0; j2 < 16; ++j2) a += red[t * 16 + j2];
            const int u = bid * 12 + t;
            cs[(u >> 9) * DD + (u & 511)] = a;
        }
        __syncthreads();
    }

    // Phase B2: gemm tile
    gemm_body(pl, w, part, bid, (unsigned short*)L);

    __threadfence();
    grid.sync();

    // Phase C: epilogue
    const int base = bid * 256 + t;
    rank1_store(base,          part, w, pw, cs, out);
    rank1_store(base + 131072, part, w, pw, cs, out);
    if (bid == 0) {
        deltab_store(t,       bvec, pb, cs, out);
        deltab_store(t + 256, bvec, pb, cs, out);
    }
}

// ===========================================================================
// Fallback: R4-verified 5-kernel path (identical math)
// ===========================================================================
__global__ __launch_bounds__(256, 3) void prep3_kernel(
    const float* __restrict__ x, const float* __restrict__ s,
    const float* __restrict__ y, const float* __restrict__ pw,
    unsigned short* __restrict__ pl, float* __restrict__ csp)
{
    __shared__ __align__(16) char L[5 * 8192];
    prep_unit(x, s, y, pw, pl, csp, blockIdx.x, blockIdx.y, L);
}

__global__ __launch_bounds__(256) void reduce_cs_kernel(
    const float* __restrict__ csp, float* __restrict__ cs)
{
    const int u = blockIdx.x * 256 + threadIdx.x;
    if (u < 12 * DD) {
        const int v = u >> 9;
        const int c = u & 511;
        const int colq = c >> 6, cl = c & 63;
        float acc = 0.f;
        for (int bt = 0; bt < 128; ++bt)
            acc += csp[((size_t)(bt * 8 + colq) * 12 + v) * 64 + cl];
        cs[v * DD + c] = acc;
    }
}

__global__ __launch_bounds__(256, 2) void gemm_kernel(
    const unsigned short* __restrict__ pl, const float* __restrict__ w,
    float* __restrict__ part)
{
    __shared__ unsigned short lds[4][8192];
    gemm_body(pl, w, part, blockIdx.x, &lds[0][0]);
}

__global__ __launch_bounds__(256) void reduce_rank1_kernel(
    const float* __restrict__ part, const float* __restrict__ w,
    const float* __restrict__ pw, const float* __restrict__ cs,
    float* __restrict__ out)
{
    rank1_store(blockIdx.x * 256 + threadIdx.x, part, w, pw, cs, out);
}

__global__ __launch_bounds__(256) void deltab_kernel(
    const float* __restrict__ bvec, const float* __restrict__ pb,
    const float* __restrict__ cs, float* __restrict__ out)
{
    const int o = blockIdx.x * 256 + threadIdx.x;
    if (o < DD) deltab_store(o, bvec, pb, cs, out);
}

extern "C" void kernel_launch(void* const* d_in, const int* in_sizes, int n_in,
                              void* d_out, int out_size, void* d_ws, size_t ws_size,
                              hipStream_t stream) {
    const float* x  = (const float*)d_in[0];
    const float* s  = (const float*)d_in[1];
    const float* y  = (const float*)d_in[2];
    const float* w  = (const float*)d_in[3];
    const float* b  = (const float*)d_in[4];
    const float* pw = (const float*)d_in[5];
    const float* pb = (const float*)d_in[6];
    float* out = (float*)d_out;

    const size_t planeBytes = (size_t)PLANE * 2 * NPLANES;            // 41.9 MB
    const size_t partBytes  = (size_t)KSPLIT * NELEM * sizeof(float); // 33.6 MB
    const size_t cspBytes   = (size_t)1024 * 12 * 64 * sizeof(float); //  3.1 MB

    unsigned short* pl = (unsigned short*)d_ws;
    float* part = (float*)((char*)d_ws + planeBytes);
    float* csp  = (float*)((char*)d_ws + planeBytes + partBytes);
    float* cs   = (float*)((char*)d_ws + planeBytes + partBytes + cspBytes);

    void* args[] = { (void*)&x, (void*)&s, (void*)&y, (void*)&w, (void*)&b,
                     (void*)&pw, (void*)&pb, (void*)&pl, (void*)&part,
                     (void*)&csp, (void*)&cs, (void*)&out };
    hipError_t err = hipLaunchCooperativeKernel(
        (const void*)fused_all, dim3(512), dim3(256), args, 0, stream);

    if (err != hipSuccess) {
        (void)hipGetLastError();   // clear sticky error, use fallback path
        prep3_kernel<<<dim3(8, 128), 256, 0, stream>>>(x, s, y, pw, pl, csp);
        reduce_cs_kernel<<<24, 256, 0, stream>>>(csp, cs);
        gemm_kernel<<<512, 256, 0, stream>>>(pl, w, part);
        reduce_rank1_kernel<<<1024, 256, 0, stream>>>(part, w, pw, cs, out);
        deltab_kernel<<<2, 256, 0, stream>>>(b, pb, cs, out);
    }
}

// Round 6
// 139.954 us; speedup vs baseline: 2.7998x; 2.7998x over previous
//
#include <hip/hip_runtime.h>

#define BD 8192
#define DD 512
#define PLANE (BD * DD)          // 4194304 elems per bf16 plane
#define NPLANES 5                // 0:A1 1:A2 2:A3 3:x 4:x^2
#define KSPLIT 32
#define NELEM (DD * DD)          // 262144

typedef __attribute__((ext_vector_type(4))) float f32x4;
typedef __attribute__((ext_vector_type(8))) short short8;

__device__ __forceinline__ float polyev2(float c0, float c1, float c2, float w, float w2) {
    return c0 + c1 * w + c2 * w2;
}

// float -> bf16 bits, round-to-nearest-even
__device__ __forceinline__ unsigned short f2b(float v) {
    unsigned u = __builtin_bit_cast(unsigned, v);
    u += 0x7FFFu + ((u >> 16) & 1u);
    return (unsigned short)(u >> 16);
}

__device__ __forceinline__ void gload_lds16(const unsigned short* g, unsigned short* l) {
    __builtin_amdgcn_global_load_lds((__attribute__((address_space(1))) const void*)g,
                                     (__attribute__((address_space(3))) void*)l, 16, 0, 0);
}

// ===========================================================================
// Plane layout (bf16): elem addr = p*PLANE + (bt*512 + C)*64 + ((k>>3)^(C&7))*8 + (k&7)
//   bt = K-tile of 64 rows, C = column, k = row%64. XOR slot swizzle makes the
//   gemm ds_read_b128 column-slice reads bank-conflict-free; global image IS the
//   LDS image so gload_lds stages linearly (both-sides-or-neither, rule #21).
// NOTE (R5 lesson): phases communicate through kernel boundaries, NOT grid.sync —
//   cooperative fusion forced cross-XCD coherence on all traffic (294us, 532GB/s).
// ===========================================================================

// One 64-row x 64-col prep unit (verified R4/R5). Uses 40960 B of L.
__device__ __forceinline__ void prep_unit(
    const float* __restrict__ x, const float* __restrict__ s,
    const float* __restrict__ y, const float* __restrict__ pw,
    unsigned short* __restrict__ pl, float* __restrict__ csp,
    const int colq, const int bt, char* L)
{
    const int t      = threadIdx.x;
    const int colL4  = (t & 15) * 4;
    const int rg     = t >> 4;
    const int kl     = rg * 4;
    const int c0     = colq * 64;
    const int r0     = bt * 64;

    const float p23 = pw[23], p24 = pw[24], p25 = pw[25], p26 = pw[26], p27 = pw[27];
    const float p28 = pw[28], p29 = pw[29], p32 = pw[32], p33 = pw[33];

    float sm[12][4];
#pragma unroll
    for (int v = 0; v < 12; ++v)
#pragma unroll
        for (int cc = 0; cc < 4; ++cc) sm[v][cc] = 0.f;

    unsigned pk[NPLANES][4][2];

#pragma unroll
    for (int j = 0; j < 4; ++j) {
        const int row = r0 + kl + j;
        const float4 xv = *(const float4*)&x[(size_t)row * DD + c0 + colL4];
        const float4 sv = *(const float4*)&s[(size_t)row * DD + c0 + colL4];
        const float4 yv = *(const float4*)&y[(size_t)row * DD + c0 + colL4];
        const float xa[4] = {xv.x, xv.y, xv.z, xv.w};
        const float sa[4] = {sv.x, sv.y, sv.z, sv.w};
        const float ya[4] = {yv.x, yv.y, yv.z, yv.w};
#pragma unroll
        for (int cc = 0; cc < 4; ++cc) {
            const float X = xa[cc], S = sa[cc], Y = ya[cc];
            const float X2 = X * X, S2 = S * S, Y2 = Y * Y, SY = S * Y;
            sm[0][cc] += X;  sm[1][cc] += X2;      sm[2][cc] += X2 * X;
            sm[3][cc] += S;  sm[4][cc] += S2;      sm[5][cc] += S2 * S;
            sm[6][cc] += Y;  sm[7][cc] += Y2;      sm[8][cc] += Y2 * Y;
            sm[9][cc] += SY; sm[10][cc] += S2 * Y; sm[11][cc] += S * Y2;
            unsigned short tv[NPLANES];
            tv[0] = f2b(p26 * S + p23 * Y + p29 * S2 + p25 * Y2 + p28 * SY);
            tv[1] = f2b(p33 * S + p32 * Y);
            tv[2] = f2b(p27 * S + p24 * Y);
            tv[3] = f2b(X);
            tv[4] = f2b(X2);
            if ((j & 1) == 0) {
#pragma unroll
                for (int p = 0; p < NPLANES; ++p) pk[p][cc][j >> 1] = (unsigned)tv[p];
            } else {
#pragma unroll
                for (int p = 0; p < NPLANES; ++p) pk[p][cc][j >> 1] |= (unsigned)tv[p] << 16;
            }
        }
    }

#pragma unroll
    for (int p = 0; p < NPLANES; ++p) {
#pragma unroll
        for (int cc = 0; cc < 4; ++cc) {
            const int colL = colL4 + cc;
            const int addr = p * 8192 + colL * 128 + (((kl >> 3) ^ (colL & 7)) << 4) + ((kl & 4) << 1);
            uint2 u; u.x = pk[p][cc][0]; u.y = pk[p][cc][1];
            *(uint2*)&L[addr] = u;
        }
    }
    __syncthreads();

    // contiguous LDS -> global copy: 10 x 16B per thread
    {
        char* gbase = (char*)pl;
        const size_t blockByte = ((size_t)bt * DD + c0) * 128;
#pragma unroll
        for (int u = 0; u < 10; ++u) {
            const int byteoff = u * 4096 + t * 16;
            const int p = byteoff >> 13;
            const int within = byteoff & 8191;
            *(uint4*)(gbase + ((size_t)p * PLANE) * 2 + blockByte + within) =
                *(const uint4*)&L[byteoff];
        }
    }
    __syncthreads();

    // column sums: in-wave (^16,^32) then cross-wave via LDS
#pragma unroll
    for (int v = 0; v < 12; ++v)
#pragma unroll
        for (int cc = 0; cc < 4; ++cc) {
            sm[v][cc] += __shfl_xor(sm[v][cc], 16, 64);
            sm[v][cc] += __shfl_xor(sm[v][cc], 32, 64);
        }
    float* R = (float*)L;
    const int wv = t >> 6, ln = t & 63;
    if (ln < 16) {
#pragma unroll
        for (int v = 0; v < 12; ++v)
#pragma unroll
            for (int cc = 0; cc < 4; ++cc)
                R[(wv * 16 + ln) * 48 + v * 4 + cc] = sm[v][cc];
    }
    __syncthreads();
    if (t < 16) {
        const int blk = bt * 8 + colq;
#pragma unroll
        for (int v = 0; v < 12; ++v)
#pragma unroll
            for (int cc = 0; cc < 4; ++cc) {
                float a = R[(0 * 16 + t) * 48 + v * 4 + cc]
                        + R[(1 * 16 + t) * 48 + v * 4 + cc]
                        + R[(2 * 16 + t) * 48 + v * 4 + cc]
                        + R[(3 * 16 + t) * 48 + v * 4 + cc];
                csp[((size_t)blk * 12 + v) * 64 + t * 4 + cc] = a;
            }
    }
}

__global__ __launch_bounds__(256, 3) void prep3_kernel(
    const float* __restrict__ x, const float* __restrict__ s,
    const float* __restrict__ y, const float* __restrict__ pw,
    unsigned short* __restrict__ pl, float* __restrict__ csp)
{
    __shared__ __align__(16) char L[5 * 8192];
    prep_unit(x, s, y, pw, pl, csp, blockIdx.x, blockIdx.y, L);
}

// cs[v][c] = sum over 128 bt-partials
__global__ __launch_bounds__(256) void reduce_cs_kernel(
    const float* __restrict__ csp, float* __restrict__ cs)
{
    const int u = blockIdx.x * 256 + threadIdx.x;
    if (u < 12 * DD) {
        const int v = u >> 9;
        const int c = u & 511;
        const int colq = c >> 6, cl = c & 63;
        float acc = 0.f;
        for (int bt = 0; bt < 128; ++bt)
            acc += csp[((size_t)(bt * 8 + colq) * 12 + v) * 64 + cl];
        cs[v * DD + c] = acc;
    }
}

// --------------------------- fused 2-acc GEMM ------------------------------
__device__ __forceinline__ void do_tile(
    const unsigned short* __restrict__ A, const unsigned short* __restrict__ B,
    int wo, int wi, int l15, int g4, f32x4 (&acc)[4][4])
{
#pragma unroll
    for (int ss = 0; ss < 2; ++ss) {
        short8 af[4], bf[4];
#pragma unroll
        for (int m = 0; m < 4; ++m) {
            const int r = wo + m * 16 + l15;
            af[m] = *(const short8*)((const char*)A + (r << 7) + ((((ss << 2) + g4) ^ (r & 7)) << 4));
        }
#pragma unroll
        for (int n = 0; n < 4; ++n) {
            const int r = wi + n * 16 + l15;
            bf[n] = *(const short8*)((const char*)B + (r << 7) + ((((ss << 2) + g4) ^ (r & 7)) << 4));
        }
#pragma unroll
        for (int m = 0; m < 4; ++m)
#pragma unroll
            for (int n = 0; n < 4; ++n)
                acc[m][n] = __builtin_amdgcn_mfma_f32_16x16x32_bf16(af[m], bf[n], acc[m][n], 0, 0, 0);
    }
}

// grid 512 (1D). ks = (bid&7) + 8*(bid>>7) groups same-ks blocks per XCD.
__global__ __launch_bounds__(256, 2) void gemm_kernel(
    const unsigned short* __restrict__ pl, const float* __restrict__ w,
    float* __restrict__ part)
{
    __shared__ unsigned short lds[4][8192];
    unsigned short* ldsp = &lds[0][0];

    const int t    = threadIdx.x;
    const int lane = t & 63;
    const int wid  = t >> 6;
    const int bid  = blockIdx.x;
    const int ks   = (bid & 7) + ((bid >> 7) << 3);
    const int tile = (bid >> 3) & 15;
    const int tileI = tile & 3;
    const int tileO = tile >> 2;
    const int wo = (wid >> 1) * 64, wi = (wid & 1) * 64;
    const int l15 = lane & 15, g4 = lane >> 4;

    const unsigned short* Am = pl + (size_t)(ks < 16 ? 0 : 1) * PLANE;
    const unsigned short* Bm = pl + (size_t)(ks < 16 ? 3 : 4) * PLANE;
    const unsigned short* Aw = pl + (size_t)2 * PLANE;
    const unsigned short* Bx = pl + (size_t)3 * PLANE;
    const int btm0 = (ks & 15) * 8;
    const int btw0 = ks * 4;

    f32x4 accM[4][4], accW[4][4];
#pragma unroll
    for (int m = 0; m < 4; ++m)
#pragma unroll
        for (int n = 0; n < 4; ++n) { accM[m][n] = (f32x4)0.f; accW[m][n] = (f32x4)0.f; }

    auto Abase = [&](int j) -> const unsigned short* {
        return (j < 8) ? Am + ((size_t)(btm0 + j) * DD + tileO * 128) * 64
                       : Aw + ((size_t)(btw0 + j - 8) * DD + tileO * 128) * 64;
    };
    auto Bbase = [&](int j) -> const unsigned short* {
        return (j < 8) ? Bm + ((size_t)(btm0 + j) * DD + tileI * 128) * 64
                       : Bx + ((size_t)(btw0 + j - 8) * DD + tileI * 128) * 64;
    };
    auto stage = [&](const unsigned short* Ag, const unsigned short* Bg, int buf) {
        unsigned short* La = ldsp + (buf * 2 + 0) * 8192;
        unsigned short* Lb = ldsp + (buf * 2 + 1) * 8192;
#pragma unroll
        for (int c = 0; c < 4; ++c) {
            gload_lds16(Ag + c * 2048 + t * 8, La + c * 2048 + wid * 512);
            gload_lds16(Bg + c * 2048 + t * 8, Lb + c * 2048 + wid * 512);
        }
    };

    stage(Abase(0), Bbase(0), 0);
    __syncthreads();
#pragma unroll 1
    for (int j = 0; j < 8; ++j) {
        const int cur = j & 1;
        stage(Abase(j + 1), Bbase(j + 1), cur ^ 1);
        do_tile(ldsp + (cur * 2 + 0) * 8192, ldsp + (cur * 2 + 1) * 8192, wo, wi, l15, g4, accM);
        __syncthreads();
    }
#pragma unroll 1
    for (int j = 8; j < 12; ++j) {
        const int cur = j & 1;
        if (j < 11) stage(Abase(j + 1), Bbase(j + 1), cur ^ 1);
        do_tile(ldsp + (cur * 2 + 0) * 8192, ldsp + (cur * 2 + 1) * 8192, wo, wi, l15, g4, accW);
        __syncthreads();
    }

    float* pout = part + (size_t)ks * NELEM;
#pragma unroll
    for (int m = 0; m < 4; ++m) {
        const int o = tileO * 128 + wo + m * 16 + g4 * 4;
#pragma unroll
        for (int n = 0; n < 4; ++n) {
            const int i = tileI * 128 + wi + n * 16 + l15;
#pragma unroll
            for (int r = 0; r < 4; ++r) {
                const float wv = w[(size_t)(o + r) * DD + i];
                pout[(size_t)(o + r) * DD + i] = accM[m][n][r] + wv * accW[m][n][r];
            }
        }
    }
}

// ------------------------- epilogue (vectorized x4 + deltab) ---------------
__device__ __forceinline__ void deltab_store(
    const int o, const float* __restrict__ bvec, const float* __restrict__ pb,
    const float* __restrict__ cs, float* __restrict__ out)
{
    const float bv = bvec[o];
    const float b2 = bv * bv, b3 = b2 * bv;
    const float invB = 1.0f / (float)BD;
    float acc = (float)BD * (pb[0] + pb[1] * bv + pb[2] * b2 + pb[3] * b3);
    acc += cs[6 * DD + o] * (pb[4] + pb[5] * bv + pb[6] * b2);
    acc += cs[7 * DD + o] * (pb[7] + pb[8] * bv);
    acc += cs[8 * DD + o] * pb[9];
    out[DD * DD + o] = invB * acc;
}

// grid 256 x 256 threads, 4 consecutive elements per thread (float4 I/O).
__global__ __launch_bounds__(256) void reduce_rank1_kernel(
    const float* __restrict__ part, const float* __restrict__ w,
    const float* __restrict__ pw, const float* __restrict__ cs,
    const float* __restrict__ bvec, const float* __restrict__ pb,
    float* __restrict__ out)
{
    const int t   = threadIdx.x;
    const int bid = blockIdx.x;
    const int idx = (bid * 256 + t) * 4;      // 0..262140, stride 4
    const int o   = idx >> 9;                  // same for all 4 lanes (512|4*256)
    const int i0  = idx & 511;

    float4 g = {0.f, 0.f, 0.f, 0.f};
#pragma unroll
    for (int ks = 0; ks < KSPLIT; ++ks) {
        const float4 p = *(const float4*)&part[(size_t)ks * NELEM + idx];
        g.x += p.x; g.y += p.y; g.z += p.z; g.w += p.w;
    }
    const float4 wv4 = *(const float4*)&w[idx];

    // o-dependent cs values (scalar, shared by the 4 lanes)
    const float csY1 = cs[6 * DD + o], csY2 = cs[7 * DD + o], csY3 = cs[8 * DD + o];
    const float csS1 = cs[3 * DD + o], csS2 = cs[4 * DD + o], csS3 = cs[5 * DD + o];
    const float csSY = cs[9 * DD + o], csS2Y = cs[10 * DD + o], csSY2 = cs[11 * DD + o];
    // i-dependent cs values (vector)
    const float4 csX1 = *(const float4*)&cs[0 * DD + i0];
    const float4 csX2 = *(const float4*)&cs[1 * DD + i0];
    const float4 csX3 = *(const float4*)&cs[2 * DD + i0];

    const float ga[4]   = {g.x, g.y, g.z, g.w};
    const float wa[4]   = {wv4.x, wv4.y, wv4.z, wv4.w};
    const float cx1[4]  = {csX1.x, csX1.y, csX1.z, csX1.w};
    const float cx2[4]  = {csX2.x, csX2.y, csX2.z, csX2.w};
    const float cx3[4]  = {csX3.x, csX3.y, csX3.z, csX3.w};

    float4 res;
    float ra[4];
#pragma unroll
    for (int l = 0; l < 4; ++l) {
        const float wv = wa[l];
        const float w2 = wv * wv, w3 = w2 * wv;
        float acc = (float)BD * (pw[0] + pw[1] * wv + pw[2] * w2 + pw[3] * w3);
        acc += cx1[l] * polyev2(pw[20], pw[21], pw[22], wv, w2);
        acc += cx2[l] * (pw[30] + pw[31] * wv);
        acc += cx3[l] * pw[34];
        acc += csY1 * polyev2(pw[4],  pw[5],  pw[6],  wv, w2);
        acc += csY2 * (pw[7] + pw[8] * wv);
        acc += csY3 * pw[9];
        acc += csS1 * polyev2(pw[10], pw[11], pw[12], wv, w2);
        acc += csSY * (pw[13] + pw[14] * wv);
        acc += csSY2 * pw[15];
        acc += csS2 * (pw[16] + pw[17] * wv);
        acc += csS2Y * pw[18];
        acc += csS3 * pw[19];
        ra[l] = (1.0f / (float)BD) * (ga[l] + acc);
    }
    res.x = ra[0]; res.y = ra[1]; res.z = ra[2]; res.w = ra[3];
    *(float4*)&out[idx] = res;

    if (bid == 0) {          // delta_b folded in (cs is ready: reduce_cs ran earlier)
        deltab_store(t,       bvec, pb, cs, out);
        deltab_store(t + 256, bvec, pb, cs, out);
    }
}

extern "C" void kernel_launch(void* const* d_in, const int* in_sizes, int n_in,
                              void* d_out, int out_size, void* d_ws, size_t ws_size,
                              hipStream_t stream) {
    const float* x  = (const float*)d_in[0];
    const float* s  = (const float*)d_in[1];
    const float* y  = (const float*)d_in[2];
    const float* w  = (const float*)d_in[3];
    const float* b  = (const float*)d_in[4];
    const float* pw = (const float*)d_in[5];
    const float* pb = (const float*)d_in[6];
    float* out = (float*)d_out;

    const size_t planeBytes = (size_t)PLANE * 2 * NPLANES;            // 41.9 MB
    const size_t partBytes  = (size_t)KSPLIT * NELEM * sizeof(float); // 33.6 MB
    const size_t cspBytes   = (size_t)1024 * 12 * 64 * sizeof(float); //  3.1 MB
    const size_t csBytes    = 12 * DD * sizeof(float);
    if (ws_size < planeBytes + partBytes + cspBytes + csBytes) return; // ws is 256MiB in this harness

    unsigned short* pl = (unsigned short*)d_ws;
    float* part = (float*)((char*)d_ws + planeBytes);
    float* csp  = (float*)((char*)d_ws + planeBytes + partBytes);
    float* cs   = (float*)((char*)d_ws + planeBytes + partBytes + cspBytes);

    prep3_kernel<<<dim3(8, 128), 256, 0, stream>>>(x, s, y, pw, pl, csp);
    reduce_cs_kernel<<<24, 256, 0, stream>>>(csp, cs);
    gemm_kernel<<<512, 256, 0, stream>>>(pl, w, part);
    reduce_rank1_kernel<<<256, 256, 0, stream>>>(part, w, pw, cs, b, pb, out);
}

// Round 7
// 132.686 us; speedup vs baseline: 2.9531x; 1.0548x over previous
//
#include <hip/hip_runtime.h>

#define BD 8192
#define DD 512
#define PLANE (BD * DD)          // 4194304 elems per bf16 plane
#define NPLANES 5                // 0:A1 1:A2 2:A3 3:x 4:x^2
#define KSPLIT 32
#define NELEM (DD * DD)          // 262144

typedef __attribute__((ext_vector_type(4))) float f32x4;
typedef __attribute__((ext_vector_type(8))) short short8;

__device__ __forceinline__ float polyev2(float c0, float c1, float c2, float w, float w2) {
    return c0 + c1 * w + c2 * w2;
}

// float -> bf16 bits, round-to-nearest-even
__device__ __forceinline__ unsigned short f2b(float v) {
    unsigned u = __builtin_bit_cast(unsigned, v);
    u += 0x7FFFu + ((u >> 16) & 1u);
    return (unsigned short)(u >> 16);
}

__device__ __forceinline__ void gload_lds16(const unsigned short* g, unsigned short* l) {
    __builtin_amdgcn_global_load_lds((__attribute__((address_space(1))) const void*)g,
                                     (__attribute__((address_space(3))) void*)l, 16, 0, 0);
}

// ===========================================================================
// Plane layout (bf16): elem addr = p*PLANE + (bt*512 + C)*64 + ((k>>3)^(C&7))*8 + (k&7)
//   bt = K-tile of 64 rows, C = column, k = row%64. XOR slot swizzle makes the
//   gemm ds_read_b128 column-slice reads bank-conflict-free; global image IS the
//   LDS image so gload_lds stages linearly (both-sides-or-neither, rule #21).
// NOTE (R5 lesson): phases communicate through kernel boundaries, NOT grid.sync —
//   cooperative fusion forced cross-XCD coherence on all traffic (294us, 532GB/s).
// ===========================================================================

// One 64-row x 64-col prep unit (verified R4/R5/R6). Uses 40960 B of L.
__device__ __forceinline__ void prep_unit(
    const float* __restrict__ x, const float* __restrict__ s,
    const float* __restrict__ y, const float* __restrict__ pw,
    unsigned short* __restrict__ pl, float* __restrict__ csp,
    const int colq, const int bt, char* L)
{
    const int t      = threadIdx.x;
    const int colL4  = (t & 15) * 4;
    const int rg     = t >> 4;
    const int kl     = rg * 4;
    const int c0     = colq * 64;
    const int r0     = bt * 64;

    const float p23 = pw[23], p24 = pw[24], p25 = pw[25], p26 = pw[26], p27 = pw[27];
    const float p28 = pw[28], p29 = pw[29], p32 = pw[32], p33 = pw[33];

    float sm[12][4];
#pragma unroll
    for (int v = 0; v < 12; ++v)
#pragma unroll
        for (int cc = 0; cc < 4; ++cc) sm[v][cc] = 0.f;

    unsigned pk[NPLANES][4][2];

#pragma unroll
    for (int j = 0; j < 4; ++j) {
        const int row = r0 + kl + j;
        const float4 xv = *(const float4*)&x[(size_t)row * DD + c0 + colL4];
        const float4 sv = *(const float4*)&s[(size_t)row * DD + c0 + colL4];
        const float4 yv = *(const float4*)&y[(size_t)row * DD + c0 + colL4];
        const float xa[4] = {xv.x, xv.y, xv.z, xv.w};
        const float sa[4] = {sv.x, sv.y, sv.z, sv.w};
        const float ya[4] = {yv.x, yv.y, yv.z, yv.w};
#pragma unroll
        for (int cc = 0; cc < 4; ++cc) {
            const float X = xa[cc], S = sa[cc], Y = ya[cc];
            const float X2 = X * X, S2 = S * S, Y2 = Y * Y, SY = S * Y;
            sm[0][cc] += X;  sm[1][cc] += X2;      sm[2][cc] += X2 * X;
            sm[3][cc] += S;  sm[4][cc] += S2;      sm[5][cc] += S2 * S;
            sm[6][cc] += Y;  sm[7][cc] += Y2;      sm[8][cc] += Y2 * Y;
            sm[9][cc] += SY; sm[10][cc] += S2 * Y; sm[11][cc] += S * Y2;
            unsigned short tv[NPLANES];
            tv[0] = f2b(p26 * S + p23 * Y + p29 * S2 + p25 * Y2 + p28 * SY);
            tv[1] = f2b(p33 * S + p32 * Y);
            tv[2] = f2b(p27 * S + p24 * Y);
            tv[3] = f2b(X);
            tv[4] = f2b(X2);
            if ((j & 1) == 0) {
#pragma unroll
                for (int p = 0; p < NPLANES; ++p) pk[p][cc][j >> 1] = (unsigned)tv[p];
            } else {
#pragma unroll
                for (int p = 0; p < NPLANES; ++p) pk[p][cc][j >> 1] |= (unsigned)tv[p] << 16;
            }
        }
    }

#pragma unroll
    for (int p = 0; p < NPLANES; ++p) {
#pragma unroll
        for (int cc = 0; cc < 4; ++cc) {
            const int colL = colL4 + cc;
            const int addr = p * 8192 + colL * 128 + (((kl >> 3) ^ (colL & 7)) << 4) + ((kl & 4) << 1);
            uint2 u; u.x = pk[p][cc][0]; u.y = pk[p][cc][1];
            *(uint2*)&L[addr] = u;
        }
    }
    __syncthreads();

    // contiguous LDS -> global copy: 10 x 16B per thread
    {
        char* gbase = (char*)pl;
        const size_t blockByte = ((size_t)bt * DD + c0) * 128;
#pragma unroll
        for (int u = 0; u < 10; ++u) {
            const int byteoff = u * 4096 + t * 16;
            const int p = byteoff >> 13;
            const int within = byteoff & 8191;
            *(uint4*)(gbase + ((size_t)p * PLANE) * 2 + blockByte + within) =
                *(const uint4*)&L[byteoff];
        }
    }
    __syncthreads();

    // column sums: in-wave (^16,^32) then cross-wave via LDS
#pragma unroll
    for (int v = 0; v < 12; ++v)
#pragma unroll
        for (int cc = 0; cc < 4; ++cc) {
            sm[v][cc] += __shfl_xor(sm[v][cc], 16, 64);
            sm[v][cc] += __shfl_xor(sm[v][cc], 32, 64);
        }
    float* R = (float*)L;
    const int wv = t >> 6, ln = t & 63;
    if (ln < 16) {
#pragma unroll
        for (int v = 0; v < 12; ++v)
#pragma unroll
            for (int cc = 0; cc < 4; ++cc)
                R[(wv * 16 + ln) * 48 + v * 4 + cc] = sm[v][cc];
    }
    __syncthreads();
    if (t < 16) {
        const int blk = bt * 8 + colq;
#pragma unroll
        for (int v = 0; v < 12; ++v)
#pragma unroll
            for (int cc = 0; cc < 4; ++cc) {
                float a = R[(0 * 16 + t) * 48 + v * 4 + cc]
                        + R[(1 * 16 + t) * 48 + v * 4 + cc]
                        + R[(2 * 16 + t) * 48 + v * 4 + cc]
                        + R[(3 * 16 + t) * 48 + v * 4 + cc];
                csp[((size_t)blk * 12 + v) * 64 + t * 4 + cc] = a;
            }
    }
}

__global__ __launch_bounds__(256, 3) void prep3_kernel(
    const float* __restrict__ x, const float* __restrict__ s,
    const float* __restrict__ y, const float* __restrict__ pw,
    unsigned short* __restrict__ pl, float* __restrict__ csp)
{
    __shared__ __align__(16) char L[5 * 8192];
    prep_unit(x, s, y, pw, pl, csp, blockIdx.x, blockIdx.y, L);
}

// --------------------------- fused 2-acc GEMM ------------------------------
__device__ __forceinline__ void do_tile(
    const unsigned short* __restrict__ A, const unsigned short* __restrict__ B,
    int wo, int wi, int l15, int g4, f32x4 (&acc)[4][4])
{
#pragma unroll
    for (int ss = 0; ss < 2; ++ss) {
        short8 af[4], bf[4];
#pragma unroll
        for (int m = 0; m < 4; ++m) {
            const int r = wo + m * 16 + l15;
            af[m] = *(const short8*)((const char*)A + (r << 7) + ((((ss << 2) + g4) ^ (r & 7)) << 4));
        }
#pragma unroll
        for (int n = 0; n < 4; ++n) {
            const int r = wi + n * 16 + l15;
            bf[n] = *(const short8*)((const char*)B + (r << 7) + ((((ss << 2) + g4) ^ (r & 7)) << 4));
        }
#pragma unroll
        for (int m = 0; m < 4; ++m)
#pragma unroll
            for (int n = 0; n < 4; ++n)
                acc[m][n] = __builtin_amdgcn_mfma_f32_16x16x32_bf16(af[m], bf[n], acc[m][n], 0, 0, 0);
    }
}

// grid 512 (1D). ks = (bid&7) + 8*(bid>>7) groups same-ks blocks per XCD.
// Blocks 0..5 additionally reduce the csp partials into cs (float4 x 256thr x 6
// blocks = 6144 entries), hidden under the remaining 506 blocks' gemm work.
__global__ __launch_bounds__(256, 2) void gemm_kernel(
    const unsigned short* __restrict__ pl, const float* __restrict__ w,
    float* __restrict__ part, const float* __restrict__ csp,
    float* __restrict__ cs)
{
    __shared__ unsigned short lds[4][8192];
    unsigned short* ldsp = &lds[0][0];

    const int t    = threadIdx.x;
    const int lane = t & 63;
    const int wid  = t >> 6;
    const int bid  = blockIdx.x;
    const int ks   = (bid & 7) + ((bid >> 7) << 3);
    const int tile = (bid >> 3) & 15;
    const int tileI = tile & 3;
    const int tileO = tile >> 2;
    const int wo = (wid >> 1) * 64, wi = (wid & 1) * 64;
    const int l15 = lane & 15, g4 = lane >> 4;

    const unsigned short* Am = pl + (size_t)(ks < 16 ? 0 : 1) * PLANE;
    const unsigned short* Bm = pl + (size_t)(ks < 16 ? 3 : 4) * PLANE;
    const unsigned short* Aw = pl + (size_t)2 * PLANE;
    const unsigned short* Bx = pl + (size_t)3 * PLANE;
    const int btm0 = (ks & 15) * 8;
    const int btw0 = ks * 4;

    f32x4 accM[4][4], accW[4][4];
#pragma unroll
    for (int m = 0; m < 4; ++m)
#pragma unroll
        for (int n = 0; n < 4; ++n) { accM[m][n] = (f32x4)0.f; accW[m][n] = (f32x4)0.f; }

    auto Abase = [&](int j) -> const unsigned short* {
        return (j < 8) ? Am + ((size_t)(btm0 + j) * DD + tileO * 128) * 64
                       : Aw + ((size_t)(btw0 + j - 8) * DD + tileO * 128) * 64;
    };
    auto Bbase = [&](int j) -> const unsigned short* {
        return (j < 8) ? Bm + ((size_t)(btm0 + j) * DD + tileI * 128) * 64
                       : Bx + ((size_t)(btw0 + j - 8) * DD + tileI * 128) * 64;
    };
    auto stage = [&](const unsigned short* Ag, const unsigned short* Bg, int buf) {
        unsigned short* La = ldsp + (buf * 2 + 0) * 8192;
        unsigned short* Lb = ldsp + (buf * 2 + 1) * 8192;
#pragma unroll
        for (int c = 0; c < 4; ++c) {
            gload_lds16(Ag + c * 2048 + t * 8, La + c * 2048 + wid * 512);
            gload_lds16(Bg + c * 2048 + t * 8, Lb + c * 2048 + wid * 512);
        }
    };

    stage(Abase(0), Bbase(0), 0);
    __syncthreads();
#pragma unroll 1
    for (int j = 0; j < 8; ++j) {
        const int cur = j & 1;
        stage(Abase(j + 1), Bbase(j + 1), cur ^ 1);
        do_tile(ldsp + (cur * 2 + 0) * 8192, ldsp + (cur * 2 + 1) * 8192, wo, wi, l15, g4, accM);
        __syncthreads();
    }
#pragma unroll 1
    for (int j = 8; j < 12; ++j) {
        const int cur = j & 1;
        if (j < 11) stage(Abase(j + 1), Bbase(j + 1), cur ^ 1);
        do_tile(ldsp + (cur * 2 + 0) * 8192, ldsp + (cur * 2 + 1) * 8192, wo, wi, l15, g4, accW);
        __syncthreads();
    }

    float* pout = part + (size_t)ks * NELEM;
#pragma unroll
    for (int m = 0; m < 4; ++m) {
        const int o = tileO * 128 + wo + m * 16 + g4 * 4;
#pragma unroll
        for (int n = 0; n < 4; ++n) {
            const int i = tileI * 128 + wi + n * 16 + l15;
#pragma unroll
            for (int r = 0; r < 4; ++r) {
                const float wv = w[(size_t)(o + r) * DD + i];
                pout[(size_t)(o + r) * DD + i] = accM[m][n][r] + wv * accW[m][n][r];
            }
        }
    }

    // folded column-sum reduction (was reduce_cs_kernel): 6 blocks x 256thr x 4
    if (bid < 6) {
        const int u4 = (bid * 256 + t) * 4;         // 0..6140, multiple of 4
        const int v  = u4 >> 9;
        const int c  = u4 & 511;                     // multiple of 4
        const int colq = c >> 6, cl = c & 63;
        float4 acc = {0.f, 0.f, 0.f, 0.f};
        for (int bt = 0; bt < 128; ++bt) {
            const float4 p = *(const float4*)&csp[((size_t)(bt * 8 + colq) * 12 + v) * 64 + cl];
            acc.x += p.x; acc.y += p.y; acc.z += p.z; acc.w += p.w;
        }
        *(float4*)&cs[v * DD + c] = acc;
    }
}

// ------------------------- epilogue (vectorized x4 + deltab) ---------------
__device__ __forceinline__ void deltab_store(
    const int o, const float* __restrict__ bvec, const float* __restrict__ pb,
    const float* __restrict__ cs, float* __restrict__ out)
{
    const float bv = bvec[o];
    const float b2 = bv * bv, b3 = b2 * bv;
    const float invB = 1.0f / (float)BD;
    float acc = (float)BD * (pb[0] + pb[1] * bv + pb[2] * b2 + pb[3] * b3);
    acc += cs[6 * DD + o] * (pb[4] + pb[5] * bv + pb[6] * b2);
    acc += cs[7 * DD + o] * (pb[7] + pb[8] * bv);
    acc += cs[8 * DD + o] * pb[9];
    out[DD * DD + o] = invB * acc;
}

// grid 256 x 256 threads, 4 consecutive elements per thread (float4 I/O).
__global__ __launch_bounds__(256) void reduce_rank1_kernel(
    const float* __restrict__ part, const float* __restrict__ w,
    const float* __restrict__ pw, const float* __restrict__ cs,
    const float* __restrict__ bvec, const float* __restrict__ pb,
    float* __restrict__ out)
{
    const int t   = threadIdx.x;
    const int bid = blockIdx.x;
    const int idx = (bid * 256 + t) * 4;      // 0..262140, stride 4
    const int o   = idx >> 9;                  // same for all 4 lanes (512|4*256)
    const int i0  = idx & 511;

    float4 g = {0.f, 0.f, 0.f, 0.f};
#pragma unroll
    for (int ks = 0; ks < KSPLIT; ++ks) {
        const float4 p = *(const float4*)&part[(size_t)ks * NELEM + idx];
        g.x += p.x; g.y += p.y; g.z += p.z; g.w += p.w;
    }
    const float4 wv4 = *(const float4*)&w[idx];

    // o-dependent cs values (scalar, shared by the 4 lanes)
    const float csY1 = cs[6 * DD + o], csY2 = cs[7 * DD + o], csY3 = cs[8 * DD + o];
    const float csS1 = cs[3 * DD + o], csS2 = cs[4 * DD + o], csS3 = cs[5 * DD + o];
    const float csSY = cs[9 * DD + o], csS2Y = cs[10 * DD + o], csSY2 = cs[11 * DD + o];
    // i-dependent cs values (vector)
    const float4 csX1 = *(const float4*)&cs[0 * DD + i0];
    const float4 csX2 = *(const float4*)&cs[1 * DD + i0];
    const float4 csX3 = *(const float4*)&cs[2 * DD + i0];

    const float ga[4]   = {g.x, g.y, g.z, g.w};
    const float wa[4]   = {wv4.x, wv4.y, wv4.z, wv4.w};
    const float cx1[4]  = {csX1.x, csX1.y, csX1.z, csX1.w};
    const float cx2[4]  = {csX2.x, csX2.y, csX2.z, csX2.w};
    const float cx3[4]  = {csX3.x, csX3.y, csX3.z, csX3.w};

    float4 res;
    float ra[4];
#pragma unroll
    for (int l = 0; l < 4; ++l) {
        const float wv = wa[l];
        const float w2 = wv * wv, w3 = w2 * wv;
        float acc = (float)BD * (pw[0] + pw[1] * wv + pw[2] * w2 + pw[3] * w3);
        acc += cx1[l] * polyev2(pw[20], pw[21], pw[22], wv, w2);
        acc += cx2[l] * (pw[30] + pw[31] * wv);
        acc += cx3[l] * pw[34];
        acc += csY1 * polyev2(pw[4],  pw[5],  pw[6],  wv, w2);
        acc += csY2 * (pw[7] + pw[8] * wv);
        acc += csY3 * pw[9];
        acc += csS1 * polyev2(pw[10], pw[11], pw[12], wv, w2);
        acc += csSY * (pw[13] + pw[14] * wv);
        acc += csSY2 * pw[15];
        acc += csS2 * (pw[16] + pw[17] * wv);
        acc += csS2Y * pw[18];
        acc += csS3 * pw[19];
        ra[l] = (1.0f / (float)BD) * (ga[l] + acc);
    }
    res.x = ra[0]; res.y = ra[1]; res.z = ra[2]; res.w = ra[3];
    *(float4*)&out[idx] = res;

    if (bid == 0) {          // delta_b folded in (cs is ready from gemm_kernel)
        deltab_store(t,       bvec, pb, cs, out);
        deltab_store(t + 256, bvec, pb, cs, out);
    }
}

extern "C" void kernel_launch(void* const* d_in, const int* in_sizes, int n_in,
                              void* d_out, int out_size, void* d_ws, size_t ws_size,
                              hipStream_t stream) {
    const float* x  = (const float*)d_in[0];
    const float* s  = (const float*)d_in[1];
    const float* y  = (const float*)d_in[2];
    const float* w  = (const float*)d_in[3];
    const float* b  = (const float*)d_in[4];
    const float* pw = (const float*)d_in[5];
    const float* pb = (const float*)d_in[6];
    float* out = (float*)d_out;

    const size_t planeBytes = (size_t)PLANE * 2 * NPLANES;            // 41.9 MB
    const size_t partBytes  = (size_t)KSPLIT * NELEM * sizeof(float); // 33.6 MB
    const size_t cspBytes   = (size_t)1024 * 12 * 64 * sizeof(float); //  3.1 MB
    const size_t csBytes    = 12 * DD * sizeof(float);
    if (ws_size < planeBytes + partBytes + cspBytes + csBytes) return; // ws is 256MiB here

    unsigned short* pl = (unsigned short*)d_ws;
    float* part = (float*)((char*)d_ws + planeBytes);
    float* csp  = (float*)((char*)d_ws + planeBytes + partBytes);
    float* cs   = (float*)((char*)d_ws + planeBytes + partBytes + cspBytes);

    prep3_kernel<<<dim3(8, 128), 256, 0, stream>>>(x, s, y, pw, pl, csp);
    gemm_kernel<<<512, 256, 0, stream>>>(pl, w, part, csp, cs);
    reduce_rank1_kernel<<<256, 256, 0, stream>>>(part, w, pw, cs, b, pb, out);
}